// Round 13
// baseline (92.791 us; speedup 1.0000x reference)
//
#include <hip/hip_runtime.h>
#include <math.h>

typedef __attribute__((ext_vector_type(8))) short s16x8;
typedef __attribute__((ext_vector_type(4))) float f32x4;
typedef __attribute__((ext_vector_type(2))) float f32x2;

#define LOG2E 1.4426950408889634f

// ---- workspace layout (float offsets), total ~17.7 MB ----
#define OFF_XH   0           // xh bf16 NHWC [4][4096][256] = 2,097,152 floats; ALIASED later by k_wav f32 [16384][128]
#define OFF_WB   2097152     // conv1 weights bf16 MFMA layout [ch2][ck8][tap9][g4][co64][j8] = 147,456 floats
#define OFF_PQT  2244608     // [ic16][part8][o128][4] = coalesced {A,B,P',D'} (65536 floats)
#define OFF_W2   2310144     // W2cat [21][256] = [w2 | w2@base_w]
#define OFF_H    2315520     // h f32 NHWC [16384][128]

// ---------------- fused prologue: transpose x | prep weights | w2b ---------
// blocks [0,1024): x NCHW f32 -> NHWC bf16
// blocks [1024,2251): conv1-weight bf16 repack + folded KAN params + w2 copy
// blocks [2251,2272): W2B[nc][i] = sum_o w2[nc][o]*base_w[o][i]
__global__ __launch_bounds__(256) void prep_all_k(
    const float* __restrict__ x, const float* __restrict__ w1,
    const float* __restrict__ ks, const float* __restrict__ kt,
    const float* __restrict__ kw, const float* __restrict__ kb,
    const float* __restrict__ w2, float* __restrict__ ws) {
  int blk = blockIdx.x;
  int t = threadIdx.x;
  if (blk < 1024) {
    __shared__ float lsm[64][65];
    unsigned short* xh = (unsigned short*)(ws + OFF_XH);
    int pr = blk & 63, cib = (blk >> 6) & 3, bb = blk >> 8;
    int sp0 = pr * 64;
    const float* src = x + (unsigned)(bb * 256 + cib * 64) * 4096 + sp0;
#pragma unroll
    for (int rr = 0; rr < 16; ++rr) {
      int idx = rr * 256 + t;
      int ci = idx >> 6, px = idx & 63;
      lsm[ci][px] = src[ci * 4096 + px];
    }
    __syncthreads();
#pragma unroll
    for (int rr = 0; rr < 16; ++rr) {
      int idx = rr * 256 + t;
      int px = idx >> 6, ci = idx & 63;
      unsigned u = __float_as_uint(lsm[ci][px]);
      xh[(unsigned)(bb * 4096 + sp0 + px) * 256 + cib * 64 + ci] =
          (unsigned short)((u + 0x7FFF + ((u >> 16) & 1)) >> 16);
    }
  } else if (blk < 2251) {
    // KAN folding: contribution = fma(P',h,D') * exp2(h*fma(A,h,B));
    // A=Q, B=-2QT, P'=P0*2^C, D'=-P0*T*2^C, C=QT^2, Q=-0.5*log2e/s^2, P0=-kw/s.
    // Param layout coalesced: [ic][part8][o128][4f], part={A_lo,A_hi,B_lo,...}.
    int tid = (blk - 1024) * 256 + t;
    unsigned short* Wb = (unsigned short*)(ws + OFF_WB);
    if (tid < 294912) {
      int j = tid & 7, co = (tid >> 3) & 63, g = (tid >> 9) & 3, r = tid >> 11;
      int t9 = r % 9, q = r / 9, ck = q & 7, chh = q >> 3;
      int ci = ck * 32 + g * 8 + j, cog = chh * 64 + co;
      unsigned u = __float_as_uint(w1[(unsigned)(cog * 256 + ci) * 9 + t9]);
      Wb[tid] = (unsigned short)((u + 0x7FFF + ((u >> 16) & 1)) >> 16);
    } else if (tid < 294912 + 16384) {
      int i2 = tid - 294912;
      int i = i2 >> 7, o = i2 & 127;
      int ic = i >> 3, k = i & 7;
      float rs = 1.f / ks[o * 128 + i];
      float T  = kt[o * 128 + i];
      float A  = -0.7213475204444817f * rs * rs;   // Q
      float Bq = -2.f * A * T;
      float C  = A * T * T;
      float P0 = -rs * kw[o * 128 + i];
      float sc = exp2f(C);
      int khi = k >> 2, klo = k & 3;
      unsigned base = ((unsigned)ic * 8 * 128 + o) * 4 + klo;  // + part*512
      ws[OFF_PQT + base + (0 + khi) * 512] = A;
      ws[OFF_PQT + base + (2 + khi) * 512] = Bq;
      ws[OFF_PQT + base + (4 + khi) * 512] = P0 * sc;
      ws[OFF_PQT + base + (6 + khi) * 512] = -P0 * T * sc;
    } else if (tid < 294912 + 16384 + 2688) {
      int i3 = tid - 294912 - 16384;
      int nc = i3 >> 7, k = i3 & 127;
      ws[OFF_W2 + nc * 256 + k] = w2[nc * 128 + k];
    }
  } else {
    int nc = blk - 2251;
    if (t < 128) {
      float acc = 0.f;
      for (int o = 0; o < 128; ++o)
        acc = fmaf(w2[nc * 128 + o], kb[o * 128 + t], acc);
      ws[OFF_W2 + nc * 256 + 128 + t] = acc;
    }
  }
}

// ---------------- conv1 3x3 as bf16 MFMA implicit GEMM ---------------------
// grid 512 = bb(4) x y(64) x cohalf(2); block 256 = 4 waves; 2 blocks/CU.
// block tile 64M(1y x 64x) x 64N; wave tile 32Mx32N (Mr=2, Nr=2).
__global__ __launch_bounds__(256, 2) void conv1_mfma_k(
    const unsigned short* __restrict__ xh, const unsigned short* __restrict__ Wb,
    const float* __restrict__ b1, float* __restrict__ h) {
  __shared__ unsigned short Asm[3 * 66 * 40];  // [yrow3][x66][ci 32 pad40] 15.8KB
  __shared__ unsigned short Bsm[18432];        // [tap9][g4][co64][j8]      36.9KB
  int blk = blockIdx.x;
  int ch = blk & 1, y = (blk >> 1) & 63, bb = blk >> 7;
  int t = threadIdx.x;
  int wave = t >> 6, lane = t & 63;
  int wx = wave & 1, wn = wave >> 1;
  int l15 = lane & 15, lg = lane >> 4;

  if (t < 6) {  // zero x-halo columns (stay zero across chunks)
    int r = t >> 1, xl = (t & 1) * 65;
    float4 z = {0, 0, 0, 0};
    float4* p = (float4*)&Asm[(r * 66 + xl) * 40];
    p[0] = z; p[1] = z; p[2] = z; p[3] = z; p[4] = z;
  }

  f32x4 acc[2][2];
  f32x4 zz = {0.f, 0.f, 0.f, 0.f};
  acc[0][0] = zz; acc[0][1] = zz; acc[1][0] = zz; acc[1][1] = zz;

  int r_st = t >> 6, x_st = t & 63;
  int gy = y - 1 + r_st;
  bool arow = (r_st < 3);
  bool yok = arow & (gy >= 0) & (gy < 64);
  const unsigned short* asrc = xh + (unsigned)(bb * 4096 + gy * 64 + x_st) * 256;
  unsigned short* adst = &Asm[(r_st * 66 + x_st + 1) * 40];
  const unsigned short* bslab = Wb + ch * 8 * 18432;

  for (int ck = 0; ck < 8; ++ck) {
    float4 v0 = {0, 0, 0, 0}, v1 = v0, v2 = v0, v3 = v0;
    if (yok) {
      const float4* s = (const float4*)(asrc + ck * 32);
      v0 = s[0]; v1 = s[1]; v2 = s[2]; v3 = s[3];
    }
    if (arow) { float4* d = (float4*)adst; d[0] = v0; d[1] = v1; d[2] = v2; d[3] = v3; }
    {
      const float4* s = (const float4*)(bslab + ck * 18432);
      float4* d = (float4*)Bsm;
#pragma unroll
      for (int j = 0; j < 9; ++j) d[j * 256 + t] = s[j * 256 + t];
    }
    __syncthreads();
#pragma unroll
    for (int t9 = 0; t9 < 9; ++t9) {
      int ky = t9 / 3, kx = t9 % 3;
      s16x8 a[2], b[2];
      int abase = (ky * 66 + wx * 32 + l15 + kx) * 40 + lg * 8;
#pragma unroll
      for (int f = 0; f < 2; ++f)
        a[f] = *(const s16x8*)&Asm[abase + f * 640];
#pragma unroll
      for (int n = 0; n < 2; ++n)
        b[n] = *(const s16x8*)&Bsm[((t9 * 4 + lg) * 64 + wn * 32 + n * 16 + l15) * 8];
#pragma unroll
      for (int f = 0; f < 2; ++f)
#pragma unroll
        for (int n = 0; n < 2; ++n)
          acc[f][n] = __builtin_amdgcn_mfma_f32_16x16x32_bf16(a[f], b[n], acc[f][n], 0, 0, 0);
    }
    __syncthreads();
  }
  // epilogue: bias + relu, store h NHWC f32
#pragma unroll
  for (int n = 0; n < 2; ++n) {
    int co = ch * 64 + wn * 32 + n * 16 + l15;
    float bz = b1[co];
#pragma unroll
    for (int f = 0; f < 2; ++f) {
      int xbase = wx * 32 + f * 16 + lg * 4;
      float* dst = h + (unsigned)(bb * 4096 + y * 64 + xbase) * 128 + co;
#pragma unroll
      for (int r = 0; r < 4; ++r) {
        float v = acc[f][n][r] + bz;
        dst[r * 128] = v > 0.f ? v : 0.f;
      }
    }
  }
}

// ---------------- Wav-KAN, DoG term only -----------------------------------
// r13 occupancy-cap isolation: r12's 4-wave/ic-split blocks stuck at 43%
// occupancy (busy-cycles constant ~28us; dur tracks effective residency).
// This variant removes every plausible binder: block = 2 waves (128 thr),
// wave = 64 o x 4 n x ALL 16 ic (no ic-split -> no reduction LDS, no
// second barrier, direct stores), LDS 2KB, grid 4096 = 16 blocks/CU.
// Inner math body identical to r8/r12 (proven best). Param traffic/wave
// unchanged. If occupancy still ~43%, the cap is extrinsic to block shape.
__global__ __launch_bounds__(128) void wavkan_k(
    const float* __restrict__ h, const float* __restrict__ PQT,
    float* __restrict__ kwout) {
  __shared__ float hsm[4][128];        // 2 KB
  int n0 = blockIdx.x * 4;
  int t = threadIdx.x;
  {
    int row = t >> 5, c4 = (t & 31) * 4;
    *(float4*)&hsm[row][c4] = *(const float4*)&h[(unsigned)(n0 + row) * 128 + c4];
  }
  __syncthreads();

  int wave = t >> 6, lane = t & 63;
  int o = wave * 64 + lane;

  f32x2 accv[4];
#pragma unroll
  for (int n = 0; n < 4; ++n) accv[n] = (f32x2){0.f, 0.f};

  const float4* pq = (const float4*)PQT + o;   // + (ic*8+part)*128

  for (int ic = 0; ic < 16; ++ic) {
    const float4* pp = pq + (unsigned)ic * 1024;
    float4 r0 = pp[0],   r1 = pp[128], r2 = pp[256], r3 = pp[384],
           r4 = pp[512], r5 = pp[640], r6 = pp[768], r7 = pp[896];
    f32x2 A2[4] = {{r0.x, r0.y}, {r0.z, r0.w}, {r1.x, r1.y}, {r1.z, r1.w}};
    f32x2 B2[4] = {{r2.x, r2.y}, {r2.z, r2.w}, {r3.x, r3.y}, {r3.z, r3.w}};
    f32x2 P2[4] = {{r4.x, r4.y}, {r4.z, r4.w}, {r5.x, r5.y}, {r5.z, r5.w}};
    f32x2 D2[4] = {{r6.x, r6.y}, {r6.z, r6.w}, {r7.x, r7.y}, {r7.z, r7.w}};
    int i0 = ic * 8;
#pragma unroll
    for (int n = 0; n < 4; ++n) {
      float4 h0 = *(const float4*)&hsm[n][i0];           // broadcast ds_read
      float4 h1 = *(const float4*)&hsm[n][i0 + 4];
      f32x2 hh[4] = {{h0.x, h0.y}, {h0.z, h0.w}, {h1.x, h1.y}, {h1.z, h1.w}};
      f32x2 a2 = accv[n];
#pragma unroll
      for (int q = 0; q < 4; ++q) {
        f32x2 h2 = hh[q];
        f32x2 t2 = A2[q] * h2 + B2[q];     // v_pk_fma_f32
        f32x2 u2 = t2 * h2;                // v_pk_mul_f32
        f32x2 e2;
        e2.x = __builtin_amdgcn_exp2f(u2.x);
        e2.y = __builtin_amdgcn_exp2f(u2.y);
        f32x2 v2 = P2[q] * h2 + D2[q];     // v_pk_fma_f32
        a2 = v2 * e2 + a2;                 // v_pk_fma_f32
      }
      accv[n] = a2;
    }
  }
#pragma unroll
  for (int n = 0; n < 4; ++n)
    kwout[(unsigned)(n0 + n) * 128 + o] = accv[n].x + accv[n].y;
}

// ---------------- conv2 1x1, K=256 ([k_wav | silu(h)]) ---------------------
// bounded unroll: round-4 counters showed full unroll -> 256 VGPR + spills.
__global__ __launch_bounds__(256) void conv2_k(
    const float* __restrict__ kwv, const float* __restrict__ h,
    const float* __restrict__ w2c, const float* __restrict__ b2,
    float* __restrict__ out) {
  __shared__ float ksm[32][260];    // 33.3KB
  __shared__ float wsm[21 * 256];   // 21.5KB
  int n0 = blockIdx.x * 32;
  int t = threadIdx.x;
#pragma unroll 2
  for (int rr = 0; rr < 4; ++rr) {
    int idx4 = rr * 256 + t;
    int row = idx4 >> 5, c4 = (idx4 & 31) * 4;
    *(float4*)&ksm[row][c4] = *(const float4*)&kwv[(unsigned)(n0 + row) * 128 + c4];
    float4 v = *(const float4*)&h[(unsigned)(n0 + row) * 128 + c4];
    float4 s;
    s.x = v.x * __builtin_amdgcn_rcpf(1.f + __builtin_amdgcn_exp2f(-LOG2E * v.x));
    s.y = v.y * __builtin_amdgcn_rcpf(1.f + __builtin_amdgcn_exp2f(-LOG2E * v.y));
    s.z = v.z * __builtin_amdgcn_rcpf(1.f + __builtin_amdgcn_exp2f(-LOG2E * v.z));
    s.w = v.w * __builtin_amdgcn_rcpf(1.f + __builtin_amdgcn_exp2f(-LOG2E * v.w));
    *(float4*)&ksm[row][128 + c4] = s;
  }
#pragma unroll 2
  for (int j = t; j < 1344; j += 256)
    *(float4*)&wsm[j * 4] = *(const float4*)&w2c[j * 4];
  __syncthreads();

  int n = t & 31, ncg = t >> 5;
  float a0 = 0.f, a1 = 0.f, a2 = 0.f;
  bool has2 = ncg < 5;
#pragma unroll 4
  for (int i4 = 0; i4 < 64; ++i4) {
    float4 k4 = *(const float4*)&ksm[n][i4 * 4];
    float4 wA = *(const float4*)&wsm[ncg * 256 + i4 * 4];
    float4 wB = *(const float4*)&wsm[(ncg + 8) * 256 + i4 * 4];
    a0 += k4.x * wA.x + k4.y * wA.y + k4.z * wA.z + k4.w * wA.w;
    a1 += k4.x * wB.x + k4.y * wB.y + k4.z * wB.z + k4.w * wB.w;
    if (has2) {
      float4 wC = *(const float4*)&wsm[(ncg + 16) * 256 + i4 * 4];
      a2 += k4.x * wC.x + k4.y * wC.y + k4.z * wC.z + k4.w * wC.w;
    }
  }
  int gn = n0 + n, bb = gn >> 12, sp = gn & 4095;
  out[(unsigned)(bb * 21 + ncg) * 4096 + sp] = a0 + b2[ncg];
  out[(unsigned)(bb * 21 + ncg + 8) * 4096 + sp] = a1 + b2[ncg + 8];
  if (has2) out[(unsigned)(bb * 21 + ncg + 16) * 4096 + sp] = a2 + b2[ncg + 16];
}

// ---------------- launch ---------------------------------------------------
extern "C" void kernel_launch(void* const* d_in, const int* in_sizes, int n_in,
                              void* d_out, int out_size, void* d_ws, size_t ws_size,
                              hipStream_t stream) {
  const float* x  = (const float*)d_in[0];
  const float* w1 = (const float*)d_in[1];
  const float* b1 = (const float*)d_in[2];
  const float* ks = (const float*)d_in[3];
  const float* kt = (const float*)d_in[4];
  const float* kw = (const float*)d_in[5];
  const float* kb = (const float*)d_in[6];
  const float* w2 = (const float*)d_in[7];
  const float* b2 = (const float*)d_in[8];
  float* out = (float*)d_out;
  float* ws  = (float*)d_ws;

  prep_all_k<<<2272, 256, 0, stream>>>(x, w1, ks, kt, kw, kb, w2, ws);
  conv1_mfma_k<<<512, 256, 0, stream>>>((const unsigned short*)(ws + OFF_XH),
                                        (const unsigned short*)(ws + OFF_WB),
                                        b1, ws + OFF_H);
  wavkan_k<<<4096, 128, 0, stream>>>(ws + OFF_H, ws + OFF_PQT,
                                     ws + OFF_XH /* k_wav alias */);
  conv2_k<<<512, 256, 0, stream>>>(ws + OFF_XH, ws + OFF_H, ws + OFF_W2, b2, out);
}

// Round 14
// 90.708 us; speedup vs baseline: 1.0230x; 1.0230x over previous
//
#include <hip/hip_runtime.h>
#include <math.h>

typedef __attribute__((ext_vector_type(8))) short s16x8;
typedef __attribute__((ext_vector_type(4))) float f32x4;
typedef __attribute__((ext_vector_type(2))) float f32x2;

#define LOG2E 1.4426950408889634f

// ---- workspace layout (float offsets), total ~17.7 MB ----
#define OFF_XH   0           // xh bf16 NHWC [4][4096][256] = 2,097,152 floats; ALIASED later by k_wav f32 [16384][128]
#define OFF_WB   2097152     // conv1 weights bf16 MFMA layout [ch2][ck8][tap9][g4][co64][j8] = 147,456 floats
#define OFF_PQT  2244608     // [ic16][part8][o128][4] = coalesced {A,B,P',D'} (65536 floats)
#define OFF_W2   2310144     // W2cat [21][256] = [w2 | w2@base_w]
#define OFF_H    2315520     // h f32 NHWC [16384][128]

// ---------------- fused prologue: transpose x | prep weights | w2b ---------
// blocks [0,1024): x NCHW f32 -> NHWC bf16
// blocks [1024,2251): conv1-weight bf16 repack + folded KAN params + w2 copy
// blocks [2251,2272): W2B[nc][i] = sum_o w2[nc][o]*base_w[o][i]
__global__ __launch_bounds__(256) void prep_all_k(
    const float* __restrict__ x, const float* __restrict__ w1,
    const float* __restrict__ ks, const float* __restrict__ kt,
    const float* __restrict__ kw, const float* __restrict__ kb,
    const float* __restrict__ w2, float* __restrict__ ws) {
  int blk = blockIdx.x;
  int t = threadIdx.x;
  if (blk < 1024) {
    __shared__ float lsm[64][65];
    unsigned short* xh = (unsigned short*)(ws + OFF_XH);
    int pr = blk & 63, cib = (blk >> 6) & 3, bb = blk >> 8;
    int sp0 = pr * 64;
    const float* src = x + (unsigned)(bb * 256 + cib * 64) * 4096 + sp0;
#pragma unroll
    for (int rr = 0; rr < 16; ++rr) {
      int idx = rr * 256 + t;
      int ci = idx >> 6, px = idx & 63;
      lsm[ci][px] = src[ci * 4096 + px];
    }
    __syncthreads();
#pragma unroll
    for (int rr = 0; rr < 16; ++rr) {
      int idx = rr * 256 + t;
      int px = idx >> 6, ci = idx & 63;
      unsigned u = __float_as_uint(lsm[ci][px]);
      xh[(unsigned)(bb * 4096 + sp0 + px) * 256 + cib * 64 + ci] =
          (unsigned short)((u + 0x7FFF + ((u >> 16) & 1)) >> 16);
    }
  } else if (blk < 2251) {
    // KAN folding: contribution = fma(P',h,D') * exp2(h*fma(A,h,B));
    // A=Q, B=-2QT, P'=P0*2^C, D'=-P0*T*2^C, C=QT^2, Q=-0.5*log2e/s^2, P0=-kw/s.
    // Param layout coalesced: [ic][part8][o128][4f], part={A_lo,A_hi,B_lo,...}.
    int tid = (blk - 1024) * 256 + t;
    unsigned short* Wb = (unsigned short*)(ws + OFF_WB);
    if (tid < 294912) {
      int j = tid & 7, co = (tid >> 3) & 63, g = (tid >> 9) & 3, r = tid >> 11;
      int t9 = r % 9, q = r / 9, ck = q & 7, chh = q >> 3;
      int ci = ck * 32 + g * 8 + j, cog = chh * 64 + co;
      unsigned u = __float_as_uint(w1[(unsigned)(cog * 256 + ci) * 9 + t9]);
      Wb[tid] = (unsigned short)((u + 0x7FFF + ((u >> 16) & 1)) >> 16);
    } else if (tid < 294912 + 16384) {
      int i2 = tid - 294912;
      int i = i2 >> 7, o = i2 & 127;
      int ic = i >> 3, k = i & 7;
      float rs = 1.f / ks[o * 128 + i];
      float T  = kt[o * 128 + i];
      float A  = -0.7213475204444817f * rs * rs;   // Q
      float Bq = -2.f * A * T;
      float C  = A * T * T;
      float P0 = -rs * kw[o * 128 + i];
      float sc = exp2f(C);
      int khi = k >> 2, klo = k & 3;
      unsigned base = ((unsigned)ic * 8 * 128 + o) * 4 + klo;  // + part*512
      ws[OFF_PQT + base + (0 + khi) * 512] = A;
      ws[OFF_PQT + base + (2 + khi) * 512] = Bq;
      ws[OFF_PQT + base + (4 + khi) * 512] = P0 * sc;
      ws[OFF_PQT + base + (6 + khi) * 512] = -P0 * T * sc;
    } else if (tid < 294912 + 16384 + 2688) {
      int i3 = tid - 294912 - 16384;
      int nc = i3 >> 7, k = i3 & 127;
      ws[OFF_W2 + nc * 256 + k] = w2[nc * 128 + k];
    }
  } else {
    int nc = blk - 2251;
    if (t < 128) {
      float acc = 0.f;
      for (int o = 0; o < 128; ++o)
        acc = fmaf(w2[nc * 128 + o], kb[o * 128 + t], acc);
      ws[OFF_W2 + nc * 256 + 128 + t] = acc;
    }
  }
}

// ---------------- conv1 3x3 as bf16 MFMA implicit GEMM ---------------------
// grid 512 = bb(4) x y(64) x cohalf(2); block 256 = 4 waves; 2 blocks/CU.
// block tile 64M(1y x 64x) x 64N; wave tile 32Mx32N (Mr=2, Nr=2).
__global__ __launch_bounds__(256, 2) void conv1_mfma_k(
    const unsigned short* __restrict__ xh, const unsigned short* __restrict__ Wb,
    const float* __restrict__ b1, float* __restrict__ h) {
  __shared__ unsigned short Asm[3 * 66 * 40];  // [yrow3][x66][ci 32 pad40] 15.8KB
  __shared__ unsigned short Bsm[18432];        // [tap9][g4][co64][j8]      36.9KB
  int blk = blockIdx.x;
  int ch = blk & 1, y = (blk >> 1) & 63, bb = blk >> 7;
  int t = threadIdx.x;
  int wave = t >> 6, lane = t & 63;
  int wx = wave & 1, wn = wave >> 1;
  int l15 = lane & 15, lg = lane >> 4;

  if (t < 6) {  // zero x-halo columns (stay zero across chunks)
    int r = t >> 1, xl = (t & 1) * 65;
    float4 z = {0, 0, 0, 0};
    float4* p = (float4*)&Asm[(r * 66 + xl) * 40];
    p[0] = z; p[1] = z; p[2] = z; p[3] = z; p[4] = z;
  }

  f32x4 acc[2][2];
  f32x4 zz = {0.f, 0.f, 0.f, 0.f};
  acc[0][0] = zz; acc[0][1] = zz; acc[1][0] = zz; acc[1][1] = zz;

  int r_st = t >> 6, x_st = t & 63;
  int gy = y - 1 + r_st;
  bool arow = (r_st < 3);
  bool yok = arow & (gy >= 0) & (gy < 64);
  const unsigned short* asrc = xh + (unsigned)(bb * 4096 + gy * 64 + x_st) * 256;
  unsigned short* adst = &Asm[(r_st * 66 + x_st + 1) * 40];
  const unsigned short* bslab = Wb + ch * 8 * 18432;

  for (int ck = 0; ck < 8; ++ck) {
    float4 v0 = {0, 0, 0, 0}, v1 = v0, v2 = v0, v3 = v0;
    if (yok) {
      const float4* s = (const float4*)(asrc + ck * 32);
      v0 = s[0]; v1 = s[1]; v2 = s[2]; v3 = s[3];
    }
    if (arow) { float4* d = (float4*)adst; d[0] = v0; d[1] = v1; d[2] = v2; d[3] = v3; }
    {
      const float4* s = (const float4*)(bslab + ck * 18432);
      float4* d = (float4*)Bsm;
#pragma unroll
      for (int j = 0; j < 9; ++j) d[j * 256 + t] = s[j * 256 + t];
    }
    __syncthreads();
#pragma unroll
    for (int t9 = 0; t9 < 9; ++t9) {
      int ky = t9 / 3, kx = t9 % 3;
      s16x8 a[2], b[2];
      int abase = (ky * 66 + wx * 32 + l15 + kx) * 40 + lg * 8;
#pragma unroll
      for (int f = 0; f < 2; ++f)
        a[f] = *(const s16x8*)&Asm[abase + f * 640];
#pragma unroll
      for (int n = 0; n < 2; ++n)
        b[n] = *(const s16x8*)&Bsm[((t9 * 4 + lg) * 64 + wn * 32 + n * 16 + l15) * 8];
#pragma unroll
      for (int f = 0; f < 2; ++f)
#pragma unroll
        for (int n = 0; n < 2; ++n)
          acc[f][n] = __builtin_amdgcn_mfma_f32_16x16x32_bf16(a[f], b[n], acc[f][n], 0, 0, 0);
    }
    __syncthreads();
  }
  // epilogue: bias + relu, store h NHWC f32
#pragma unroll
  for (int n = 0; n < 2; ++n) {
    int co = ch * 64 + wn * 32 + n * 16 + l15;
    float bz = b1[co];
#pragma unroll
    for (int f = 0; f < 2; ++f) {
      int xbase = wx * 32 + f * 16 + lg * 4;
      float* dst = h + (unsigned)(bb * 4096 + y * 64 + xbase) * 128 + co;
#pragma unroll
      for (int r = 0; r < 4; ++r) {
        float v = acc[f][n][r] + bz;
        dst[r * 128] = v > 0.f ? v : 0.f;
      }
    }
  }
}

// ---------------- Wav-KAN, DoG term only -----------------------------------
// r14: persistent-param design. Evidence: pipe model (8192 pk x4cyc + 4096
// exp x8cyc = 65.5K cyc/SIMD) exactly matches measured VALUBusy ~60%; the
// other 40% is param-load stall (L2 re-reads, L1 thrashed), constant across
// 6 structures. Here each wave OWNS a 16-i slice: its 64 param floats live
// in VGPRs for the whole kernel (loaded once; param traffic 512MB -> 32MB,
// no steady-state vector loads). Block = 8 waves (512 thr) = full i-range;
// o-half per block; block stages h for 64 n once (32KB LDS), loops 8-n
// tiles; per-(n,o) 8-way i-partials reduced via 16KB LDS buffer.
// grid 512 = oh(2) x nchunk(256); 2 blocks/CU; VGPR ~120 -> 4 waves/SIMD,
// but stall-free (issue-bound at the pipe floor).
__global__ __launch_bounds__(512) void wavkan_k(
    const float* __restrict__ h, const float* __restrict__ PQT,
    float* __restrict__ kwout) {
  __shared__ float hsm[64][128];       // 32 KB
  __shared__ float part[8][8][64];     // 16 KB  [ich][n][o-lane]
  int blk = blockIdx.x;
  int oh = blk & 1;
  int n0 = (blk >> 1) * 64;
  int t = threadIdx.x;
  // stage all 64 h rows once
#pragma unroll
  for (int rr = 0; rr < 4; ++rr) {
    int idx4 = rr * 512 + t;
    int row = idx4 >> 5, c4 = (idx4 & 31) * 4;
    *(float4*)&hsm[row][c4] = *(const float4*)&h[(unsigned)(n0 + row) * 128 + c4];
  }
  int wave = t >> 6, lane = t & 63;   // wave = ich (i-slice owner)
  int o = oh * 64 + lane;
  int i0 = wave * 16;
  // persistent params: ic chunks 2*wave (pa) and 2*wave+1 (pb)
  const float4* pq = (const float4*)PQT + o;
  float4 pa[8], pb[8];
  {
    const float4* ppA = pq + (unsigned)(2 * wave) * 1024;
    const float4* ppB = pq + (unsigned)(2 * wave + 1) * 1024;
#pragma unroll
    for (int j = 0; j < 8; ++j) pa[j] = ppA[j * 128];
#pragma unroll
    for (int j = 0; j < 8; ++j) pb[j] = ppB[j * 128];
  }
  __syncthreads();   // hsm ready

  int rn = t >> 6, rl = t & 63;   // reduce-phase mapping: n=rn, o-lane=rl

  for (int tile = 0; tile < 8; ++tile) {
    int nb = tile * 8;
#pragma unroll
    for (int n = 0; n < 8; ++n) {
      const float* hr = &hsm[nb + n][i0];
      float4 h0 = *(const float4*)&hr[0];    // broadcast ds_reads
      float4 h1 = *(const float4*)&hr[4];
      float4 h2 = *(const float4*)&hr[8];
      float4 h3 = *(const float4*)&hr[12];
      f32x2 a2 = (f32x2){0.f, 0.f};
      // chunk A (params pa, i = i0..i0+7)
      {
        f32x2 A2[4] = {{pa[0].x, pa[0].y}, {pa[0].z, pa[0].w}, {pa[1].x, pa[1].y}, {pa[1].z, pa[1].w}};
        f32x2 B2[4] = {{pa[2].x, pa[2].y}, {pa[2].z, pa[2].w}, {pa[3].x, pa[3].y}, {pa[3].z, pa[3].w}};
        f32x2 P2[4] = {{pa[4].x, pa[4].y}, {pa[4].z, pa[4].w}, {pa[5].x, pa[5].y}, {pa[5].z, pa[5].w}};
        f32x2 D2[4] = {{pa[6].x, pa[6].y}, {pa[6].z, pa[6].w}, {pa[7].x, pa[7].y}, {pa[7].z, pa[7].w}};
        f32x2 hh[4] = {{h0.x, h0.y}, {h0.z, h0.w}, {h1.x, h1.y}, {h1.z, h1.w}};
#pragma unroll
        for (int q = 0; q < 4; ++q) {
          f32x2 hq = hh[q];
          f32x2 t2 = A2[q] * hq + B2[q];
          f32x2 u2 = t2 * hq;
          f32x2 e2;
          e2.x = __builtin_amdgcn_exp2f(u2.x);
          e2.y = __builtin_amdgcn_exp2f(u2.y);
          f32x2 v2 = P2[q] * hq + D2[q];
          a2 = v2 * e2 + a2;
        }
      }
      // chunk B (params pb, i = i0+8..i0+15)
      {
        f32x2 A2[4] = {{pb[0].x, pb[0].y}, {pb[0].z, pb[0].w}, {pb[1].x, pb[1].y}, {pb[1].z, pb[1].w}};
        f32x2 B2[4] = {{pb[2].x, pb[2].y}, {pb[2].z, pb[2].w}, {pb[3].x, pb[3].y}, {pb[3].z, pb[3].w}};
        f32x2 P2[4] = {{pb[4].x, pb[4].y}, {pb[4].z, pb[4].w}, {pb[5].x, pb[5].y}, {pb[5].z, pb[5].w}};
        f32x2 D2[4] = {{pb[6].x, pb[6].y}, {pb[6].z, pb[6].w}, {pb[7].x, pb[7].y}, {pb[7].z, pb[7].w}};
        f32x2 hh[4] = {{h2.x, h2.y}, {h2.z, h2.w}, {h3.x, h3.y}, {h3.z, h3.w}};
#pragma unroll
        for (int q = 0; q < 4; ++q) {
          f32x2 hq = hh[q];
          f32x2 t2 = A2[q] * hq + B2[q];
          f32x2 u2 = t2 * hq;
          f32x2 e2;
          e2.x = __builtin_amdgcn_exp2f(u2.x);
          e2.y = __builtin_amdgcn_exp2f(u2.y);
          f32x2 v2 = P2[q] * hq + D2[q];
          a2 = v2 * e2 + a2;
        }
      }
      part[wave][n][lane] = a2.x + a2.y;
    }
    __syncthreads();   // partials complete
    {
      float s = part[0][rn][rl];
#pragma unroll
      for (int j = 1; j < 8; ++j) s += part[j][rn][rl];
      kwout[(unsigned)(n0 + nb + rn) * 128 + oh * 64 + rl] = s;
    }
    __syncthreads();   // part free for next tile
  }
}

// ---------------- conv2 1x1, K=256 ([k_wav | silu(h)]) ---------------------
// bounded unroll: round-4 counters showed full unroll -> 256 VGPR + spills.
__global__ __launch_bounds__(256) void conv2_k(
    const float* __restrict__ kwv, const float* __restrict__ h,
    const float* __restrict__ w2c, const float* __restrict__ b2,
    float* __restrict__ out) {
  __shared__ float ksm[32][260];    // 33.3KB
  __shared__ float wsm[21 * 256];   // 21.5KB
  int n0 = blockIdx.x * 32;
  int t = threadIdx.x;
#pragma unroll 2
  for (int rr = 0; rr < 4; ++rr) {
    int idx4 = rr * 256 + t;
    int row = idx4 >> 5, c4 = (idx4 & 31) * 4;
    *(float4*)&ksm[row][c4] = *(const float4*)&kwv[(unsigned)(n0 + row) * 128 + c4];
    float4 v = *(const float4*)&h[(unsigned)(n0 + row) * 128 + c4];
    float4 s;
    s.x = v.x * __builtin_amdgcn_rcpf(1.f + __builtin_amdgcn_exp2f(-LOG2E * v.x));
    s.y = v.y * __builtin_amdgcn_rcpf(1.f + __builtin_amdgcn_exp2f(-LOG2E * v.y));
    s.z = v.z * __builtin_amdgcn_rcpf(1.f + __builtin_amdgcn_exp2f(-LOG2E * v.z));
    s.w = v.w * __builtin_amdgcn_rcpf(1.f + __builtin_amdgcn_exp2f(-LOG2E * v.w));
    *(float4*)&ksm[row][128 + c4] = s;
  }
#pragma unroll 2
  for (int j = t; j < 1344; j += 256)
    *(float4*)&wsm[j * 4] = *(const float4*)&w2c[j * 4];
  __syncthreads();

  int n = t & 31, ncg = t >> 5;
  float a0 = 0.f, a1 = 0.f, a2 = 0.f;
  bool has2 = ncg < 5;
#pragma unroll 4
  for (int i4 = 0; i4 < 64; ++i4) {
    float4 k4 = *(const float4*)&ksm[n][i4 * 4];
    float4 wA = *(const float4*)&wsm[ncg * 256 + i4 * 4];
    float4 wB = *(const float4*)&wsm[(ncg + 8) * 256 + i4 * 4];
    a0 += k4.x * wA.x + k4.y * wA.y + k4.z * wA.z + k4.w * wA.w;
    a1 += k4.x * wB.x + k4.y * wB.y + k4.z * wB.z + k4.w * wB.w;
    if (has2) {
      float4 wC = *(const float4*)&wsm[(ncg + 16) * 256 + i4 * 4];
      a2 += k4.x * wC.x + k4.y * wC.y + k4.z * wC.z + k4.w * wC.w;
    }
  }
  int gn = n0 + n, bb = gn >> 12, sp = gn & 4095;
  out[(unsigned)(bb * 21 + ncg) * 4096 + sp] = a0 + b2[ncg];
  out[(unsigned)(bb * 21 + ncg + 8) * 4096 + sp] = a1 + b2[ncg + 8];
  if (has2) out[(unsigned)(bb * 21 + ncg + 16) * 4096 + sp] = a2 + b2[ncg + 16];
}

// ---------------- launch ---------------------------------------------------
extern "C" void kernel_launch(void* const* d_in, const int* in_sizes, int n_in,
                              void* d_out, int out_size, void* d_ws, size_t ws_size,
                              hipStream_t stream) {
  const float* x  = (const float*)d_in[0];
  const float* w1 = (const float*)d_in[1];
  const float* b1 = (const float*)d_in[2];
  const float* ks = (const float*)d_in[3];
  const float* kt = (const float*)d_in[4];
  const float* kw = (const float*)d_in[5];
  const float* kb = (const float*)d_in[6];
  const float* w2 = (const float*)d_in[7];
  const float* b2 = (const float*)d_in[8];
  float* out = (float*)d_out;
  float* ws  = (float*)d_ws;

  prep_all_k<<<2272, 256, 0, stream>>>(x, w1, ks, kt, kw, kb, w2, ws);
  conv1_mfma_k<<<512, 256, 0, stream>>>((const unsigned short*)(ws + OFF_XH),
                                        (const unsigned short*)(ws + OFF_WB),
                                        b1, ws + OFF_H);
  wavkan_k<<<512, 512, 0, stream>>>(ws + OFF_H, ws + OFF_PQT,
                                    ws + OFF_XH /* k_wav alias */);
  conv2_k<<<512, 256, 0, stream>>>(ws + OFF_XH, ws + OFF_H, ws + OFF_W2, b2, out);
}